// Round 6
// baseline (300.100 us; speedup 1.0000x reference)
//
#include <hip/hip_runtime.h>

#define NNODES 50000
#define NEDGES 800000
#define CHUNK 3125          // edges per P1/P2 block (256 blocks * 3125 = 800000)

typedef __attribute__((ext_vector_type(8))) short short8;
typedef __attribute__((ext_vector_type(4))) float floatx4;
typedef __attribute__((ext_vector_type(8))) _Float16 f16x8;

// async global->LDS, 16B per lane (global_load_lds_dwordx4).
// LDS dest MUST be wave-uniform base + lane*16.
__device__ __forceinline__ void async16(const void* g, void* l) {
    __builtin_amdgcn_global_load_lds(
        (const __attribute__((address_space(1))) unsigned int*)g,
        (__attribute__((address_space(3))) unsigned int*)l, 16, 0, 0);
}

__device__ __forceinline__ void split_bf16(float v, short& hi, short& lo) {
    unsigned u = __float_as_uint(v);
    unsigned hu = u & 0xffff0000u;
    hi = (short)(hu >> 16);
    float r = v - __uint_as_float(hu);
    lo = (short)(__float_as_uint(r) >> 16);
}

// ---------------- merged prep: wprep (224 blk) + split (6250 blk) + p1 (256 blk)

#define PREP_WBLK 224
#define PREP_SBLK 6250
#define PREP_TOT  (PREP_WBLK + PREP_SBLK + 256)

__global__ __launch_bounds__(256) void k_prep(
    const float* __restrict__ W0, short* __restrict__ W0h, short* __restrict__ W0l,
    const float* __restrict__ W1, short* __restrict__ W1h, short* __restrict__ W1l,
    const float* __restrict__ W2, short* __restrict__ W2h, short* __restrict__ W2l,
    const float* __restrict__ x, short* __restrict__ xh, short* __restrict__ xl,
    const int* __restrict__ dst, int* __restrict__ hist2d) {
    int b = blockIdx.x, t = threadIdx.x;
    if (b < PREP_WBLK) {
        // weight transpose + split
        int id = b * 256 + t;
        const float* W; short *Wh, *Wl; int K;
        if (id < 32768) { W = W0; Wh = W0h; Wl = W0l; K = 256; }
        else if (id < 49152) { id -= 32768; W = W1; Wh = W1h; Wl = W1l; K = 128; }
        else if (id < 57344) { id -= 49152; W = W2; Wh = W2h; Wl = W2l; K = 128; }
        else return;
        int F = (W == W2) ? 64 : 128;
        int f = id / K, k = id - f * K;
        short h, l;
        split_bf16(W[(size_t)k * F + f], h, l);
        Wh[id] = h;
        Wl[id] = l;
    } else if (b < PREP_WBLK + PREP_SBLK) {
        // x fp32 -> hi/lo bf16, 8 elems/thread
        int i = (b - PREP_WBLK) * 256 + t;
        float4 v0 = ((const float4*)x)[i * 2];
        float4 v1 = ((const float4*)x)[i * 2 + 1];
        float va[8] = {v0.x, v0.y, v0.z, v0.w, v1.x, v1.y, v1.z, v1.w};
        short8 h8, l8;
#pragma unroll
        for (int j = 0; j < 8; j++) {
            short h, l;
            split_bf16(va[j], h, l);
            h8[j] = h; l8[j] = l;
        }
        *(short8*)&xh[i * 8] = h8;
        *(short8*)&xl[i * 8] = l8;
    } else {
        // P1: per-block coarse histogram of dst>>8 (no global atomics)
        __shared__ int h[256];
        int bb = b - PREP_WBLK - PREP_SBLK;
        h[t] = 0;
        __syncthreads();
        int e0 = bb * CHUNK;
#pragma unroll
        for (int k = 0; k < 13; k++) {
            int o = k * 256 + t;
            if (o < CHUNK) atomicAdd(&h[dst[e0 + o] >> 8], 1);
        }
        __syncthreads();
        hist2d[bb * 256 + t] = h[t];
    }
}

// coarse scan: sum hist2d -> chist, exclusive -> coff/ccur; rowptr[N]=E
__global__ void k_cscan(const int* __restrict__ hist2d, int* __restrict__ chist,
                        int* __restrict__ coff, int* __restrict__ ccur,
                        int* __restrict__ rowptr) {
    __shared__ int s[256];
    int t = threadIdx.x;
    int v = 0;
#pragma unroll 8
    for (int b = 0; b < 256; b++) v += hist2d[b * 256 + t];
    chist[t] = v;
    s[t] = v; __syncthreads();
    for (int o = 1; o < 256; o <<= 1) {
        int x = (t >= o) ? s[t - o] : 0;
        __syncthreads();
        s[t] += x;
        __syncthreads();
    }
    int excl = s[t] - v;
    coff[t] = excl;
    ccur[t] = excl;
    if (t == 0) rowptr[NNODES] = NEDGES;
}

// P2: scatter packed (src | (dst&255)<<16) into coarse buckets.
__global__ __launch_bounds__(256) void k_p2(const int* __restrict__ src,
                                            const int* __restrict__ dst,
                                            int* ccur, unsigned* __restrict__ buck) {
    __shared__ int hist[256];
    __shared__ int base[256];
    int t = threadIdx.x, b = blockIdx.x;
    hist[t] = 0;
    __syncthreads();
    int e0 = b * CHUNK;
    int myb[13]; int myi[13]; unsigned pk[13];
#pragma unroll
    for (int k = 0; k < 13; k++) {
        int o = k * 256 + t;
        if (o < CHUNK) {
            int s = src[e0 + o], d = dst[e0 + o];
            int bin = d >> 8;
            myb[k] = bin;
            myi[k] = atomicAdd(&hist[bin], 1);
            pk[k] = (unsigned)s | ((unsigned)(d & 255) << 16);
        }
    }
    __syncthreads();
    base[t] = hist[t] ? atomicAdd(&ccur[t], hist[t]) : 0;
    __syncthreads();
#pragma unroll
    for (int k = 0; k < 13; k++) {
        int o = k * 256 + t;
        if (o < CHUNK) buck[base[myb[k]] + myi[k]] = pk[k];
    }
}

// P3: one block per coarse bucket. Exact counts/rowptr/dinv + final scatter.
__global__ __launch_bounds__(256) void k_p3(const unsigned* __restrict__ buck,
                                            const int* __restrict__ coff,
                                            const int* __restrict__ chist,
                                            int* __restrict__ rowptr,
                                            float* __restrict__ dinv,
                                            int* __restrict__ ssrc) {
    __shared__ int h[256], ex[256], cur[256];
    int t = threadIdx.x, b = blockIdx.x;
    int s0 = coff[b], S = chist[b];
    h[t] = 0;
    __syncthreads();
    for (int i = t; i < S; i += 256)
        atomicAdd(&h[(buck[s0 + i] >> 16) & 255], 1);
    __syncthreads();
    int v = h[t];
    ex[t] = v; __syncthreads();
    for (int o = 1; o < 256; o <<= 1) {
        int x = (t >= o) ? ex[t - o] : 0;
        __syncthreads();
        ex[t] += x;
        __syncthreads();
    }
    int excl = ex[t] - v;
    int n = b * 256 + t;
    if (n < NNODES) {
        rowptr[n] = s0 + excl;
        dinv[n] = rsqrtf((float)v + 1.0f);
    }
    cur[t] = excl;
    __syncthreads();
    for (int i = t; i < S; i += 256) {
        unsigned pk = buck[s0 + i];
        int dl = (pk >> 16) & 255;
        int p = atomicAdd(&cur[dl], 1);
        ssrc[s0 + p] = (int)(pk & 0xFFFFu);
    }
}

// ---------------- GEMM: g16 = fp16((A @ W) * dinv[row]) ------------------
// A hi/lo bf16 (M x K), B = W^T hi/lo (BN x K), out fp16 (M x BN).
// BM=64, BK=64, 256 thr = 4 waves; XOR-swizzled LDS (16B blocks).

template <int BN>
__global__ __launch_bounds__(256) void k_gemm2(
    const short* __restrict__ Ah, const short* __restrict__ Al,
    const short* __restrict__ Bh, const short* __restrict__ Bl,
    const float* __restrict__ dinv, _Float16* __restrict__ g16,
    int M, int K) {
    constexpr int BM = 64, BK = 64;
    constexpr int NT = BN / 16;
    __shared__ __align__(16) short sAh[BM * BK], sAl[BM * BK];
    __shared__ __align__(16) short sBh[BN * BK], sBl[BN * BK];

    const int tid = threadIdx.x, lane = tid & 63, w = tid >> 6;
    const int row0 = blockIdx.x * BM;
    const int lr = lane >> 3;
    const int lz = lane & 7;
    const int swz = (lz ^ lr) * 8;
    const int fr = lane & 15, fq = lane >> 4;

    floatx4 acc[NT] = {};

    for (int k0 = 0; k0 < K; k0 += BK) {
#pragma unroll
        for (int jj = 0; jj < 2; jj++) {
            int j = w * 2 + jj;
            int grow = row0 + j * 8 + lr;
            if (grow >= M) grow = M - 1;
            size_t go = (size_t)grow * K + k0 + swz;
            async16(&Ah[go], &sAh[j * 8 * BK + lane * 8]);
            async16(&Al[go], &sAl[j * 8 * BK + lane * 8]);
        }
#pragma unroll
        for (int jj = 0; jj < BN / 32; jj++) {
            int j = w * (BN / 32) + jj;
            size_t go = (size_t)(j * 8 + lr) * K + k0 + swz;
            async16(&Bh[go], &sBh[j * 8 * BK + lane * 8]);
            async16(&Bl[go], &sBl[j * 8 * BK + lane * 8]);
        }
        __syncthreads();

#pragma unroll
        for (int ks = 0; ks < 2; ks++) {
            int R = w * 16 + fr;
            int ca = ((ks * 4 + fq) ^ (R & 7)) * 8;
            short8 ah = *(const short8*)&sAh[R * BK + ca];
            short8 al = *(const short8*)&sAl[R * BK + ca];
#pragma unroll
            for (int nt = 0; nt < NT; nt++) {
                int n = nt * 16 + fr;
                int cb = ((ks * 4 + fq) ^ (n & 7)) * 8;
                short8 bh = *(const short8*)&sBh[n * BK + cb];
                short8 bl = *(const short8*)&sBl[n * BK + cb];
                acc[nt] = __builtin_amdgcn_mfma_f32_16x16x32_bf16(ah, bh, acc[nt], 0, 0, 0);
                acc[nt] = __builtin_amdgcn_mfma_f32_16x16x32_bf16(ah, bl, acc[nt], 0, 0, 0);
                acc[nt] = __builtin_amdgcn_mfma_f32_16x16x32_bf16(al, bh, acc[nt], 0, 0, 0);
            }
        }
        __syncthreads();
    }

#pragma unroll
    for (int rr = 0; rr < 4; rr++) {
        int grow = row0 + w * 16 + fq * 4 + rr;
        if (grow < M) {
            float dv = dinv[grow];
#pragma unroll
            for (int nt = 0; nt < NT; nt++)
                g16[(size_t)grow * BN + nt * 16 + fr] =
                    (_Float16)(acc[nt][rr] * dv);
        }
    }
}

// ---------------- Aggregation: one wave per node, full-row gathers -------
// Lane = (slot s, chunk c): wave gathers S=64/C full rows per pass
// (C chunks of 8 fp16 = 16B each), butterfly-reduces over slot lanes.
// ssrc read once per edge; vmem request count cut C-fold vs thread-per-chunk.

template <int F>
__global__ __launch_bounds__(256) void k_aggw(const _Float16* __restrict__ g,
                                              const int* __restrict__ ssrc,
                                              const int* __restrict__ rowptr,
                                              const float* __restrict__ dinv,
                                              const float* __restrict__ bias,
                                              float* __restrict__ outf,
                                              short* __restrict__ oh,
                                              short* __restrict__ ol,
                                              int relu, int writebf) {
    constexpr int C = F / 8;       // 16B chunks per row: 16 (F=128) or 8 (F=64)
    constexpr int S = 64 / C;      // row slots per wave: 4 or 8
    int wid = (blockIdx.x * 256 + threadIdx.x) >> 6;
    if (wid >= NNODES) return;
    int lane = threadIdx.x & 63;
    int c = lane & (C - 1);
    int s = lane / C;
    int n = wid;
    const f16x8* gp = (const f16x8*)g;

    float acc[8];
    if (s == 0) {
        f16x8 v = gp[(size_t)n * C + c];          // self term
#pragma unroll
        for (int j = 0; j < 8; j++) acc[j] = (float)v[j];
    } else {
#pragma unroll
        for (int j = 0; j < 8; j++) acc[j] = 0.f;
    }

    int e0 = rowptr[n], e1 = rowptr[n + 1];
    for (int e = e0 + s; e < e1; e += S) {
        int sn = ssrc[e];
        f16x8 v = gp[(size_t)sn * C + c];
#pragma unroll
        for (int j = 0; j < 8; j++) acc[j] += (float)v[j];
    }

    // reduce over slot lanes (xor masks C..32)
#pragma unroll
    for (int m = C; m < 64; m <<= 1) {
#pragma unroll
        for (int j = 0; j < 8; j++) acc[j] += __shfl_xor(acc[j], m, 64);
    }

    if (s == 0) {
        float dv = dinv[n];
        float4 bv0 = *(const float4*)&bias[c * 8];
        float4 bv1 = *(const float4*)&bias[c * 8 + 4];
        float bb[8] = {bv0.x, bv0.y, bv0.z, bv0.w, bv1.x, bv1.y, bv1.z, bv1.w};
        float o[8];
#pragma unroll
        for (int j = 0; j < 8; j++) {
            o[j] = acc[j] * dv + bb[j];
            if (relu) o[j] = fmaxf(o[j], 0.f);
        }
        if (writebf) {
            short8 h8, l8;
#pragma unroll
            for (int j = 0; j < 8; j++) {
                short h, l;
                split_bf16(o[j], h, l);
                h8[j] = h; l8[j] = l;
            }
            *(short8*)&oh[(size_t)n * F + c * 8] = h8;
            *(short8*)&ol[(size_t)n * F + c * 8] = l8;
        } else {
            *(float4*)&outf[(size_t)n * F + c * 8] =
                make_float4(o[0], o[1], o[2], o[3]);
            *(float4*)&outf[(size_t)n * F + c * 8 + 4] =
                make_float4(o[4], o[5], o[6], o[7]);
        }
    }
}

// ---------------- launch ----------------

static inline size_t align256(size_t x) { return (x + 255) & ~(size_t)255; }

extern "C" void kernel_launch(void* const* d_in, const int* in_sizes, int n_in,
                              void* d_out, int out_size, void* d_ws, size_t ws_size,
                              hipStream_t stream) {
    const float* x  = (const float*)d_in[0];
    const int*   ei = (const int*)d_in[1];
    const float* W0 = (const float*)d_in[2];
    const float* b0 = (const float*)d_in[3];
    const float* W1 = (const float*)d_in[4];
    const float* b1 = (const float*)d_in[5];
    const float* W2 = (const float*)d_in[6];
    const float* b2 = (const float*)d_in[7];
    float* out = (float*)d_out;

    const int* src = ei;
    const int* dst = ei + NEDGES;

    char* w = (char*)d_ws;
    size_t off = 0;
    float* dinv    = (float*)(w + off); off = align256(off + NNODES * 4);
    int* rowptr    = (int*)(w + off);   off = align256(off + (NNODES + 1) * 4);
    int* hist2d    = (int*)(w + off);   off = align256(off + 256 * 256 * 4);
    int* chist     = (int*)(w + off);   off = align256(off + 256 * 4);
    int* coff      = (int*)(w + off);   off = align256(off + 256 * 4);
    int* ccur      = (int*)(w + off);   off = align256(off + 256 * 4);
    unsigned* buck = (unsigned*)(w + off); off = align256(off + (size_t)NEDGES * 4);
    int* ssrc      = (int*)(w + off);   off = align256(off + (size_t)NEDGES * 4);
    short* W0h     = (short*)(w + off); off = align256(off + 256 * 128 * 2);
    short* W0l     = (short*)(w + off); off = align256(off + 256 * 128 * 2);
    short* W1h     = (short*)(w + off); off = align256(off + 128 * 128 * 2);
    short* W1l     = (short*)(w + off); off = align256(off + 128 * 128 * 2);
    short* W2h     = (short*)(w + off); off = align256(off + 128 * 64 * 2);
    short* W2l     = (short*)(w + off); off = align256(off + 128 * 64 * 2);
    short* xh      = (short*)(w + off); off = align256(off + (size_t)NNODES * 256 * 2);
    short* xl      = (short*)(w + off); off = align256(off + (size_t)NNODES * 256 * 2);
    short* ph      = (short*)(w + off); off = align256(off + (size_t)NNODES * 128 * 2);
    short* pl      = (short*)(w + off); off = align256(off + (size_t)NNODES * 128 * 2);
    _Float16* g16  = (_Float16*)(w + off); off = align256(off + (size_t)NNODES * 128 * 2);

    // merged prep: weights + x split + coarse histogram
    k_prep<<<PREP_TOT, 256, 0, stream>>>(W0, W0h, W0l, W1, W1h, W1l,
                                         W2, W2h, W2l, x, xh, xl, dst, hist2d);
    k_cscan<<<1, 256, 0, stream>>>(hist2d, chist, coff, ccur, rowptr);
    k_p2<<<256, 256, 0, stream>>>(src, dst, ccur, buck);
    k_p3<<<256, 256, 0, stream>>>(buck, coff, chist, rowptr, dinv, ssrc);

    const int MB = (NNODES + 63) / 64;     // 782
    const int AB = (NNODES * 64 + 255) / 256;  // 12500 wave-per-node blocks

    // layer 0
    k_gemm2<128><<<MB, 256, 0, stream>>>(xh, xl, W0h, W0l, dinv, g16, NNODES, 256);
    k_aggw<128><<<AB, 256, 0, stream>>>(g16, ssrc, rowptr, dinv, b0,
                                        (float*)nullptr, ph, pl, 1, 1);
    // layer 1
    k_gemm2<128><<<MB, 256, 0, stream>>>(ph, pl, W1h, W1l, dinv, g16, NNODES, 128);
    k_aggw<128><<<AB, 256, 0, stream>>>(g16, ssrc, rowptr, dinv, b1,
                                        (float*)nullptr, ph, pl, 1, 1);
    // layer 2
    k_gemm2<64><<<MB, 256, 0, stream>>>(ph, pl, W2h, W2l, dinv, g16, NNODES, 128);
    k_aggw<64><<<AB, 256, 0, stream>>>(g16, ssrc, rowptr, dinv, b2,
                                       out, (short*)nullptr, (short*)nullptr, 0, 0);
    (void)in_sizes; (void)n_in; (void)out_size; (void)ws_size;
}